// Round 6
// baseline (1004.004 us; speedup 1.0000x reference)
//
#include <hip/hip_runtime.h>
#include <hip/hip_bf16.h>
#include <stdint.h>

#define E_SZ 300
#define H_SZ 512
#define O_SZ 5
#define B_SZ 256
#define T_SZ 200
#define PAD_IDX 1

#define KH 512
#define KE 320            // padded e-width (300 -> 320)
#define KTOT 832          // 512 + 320
#define XS_W 812          // E + H, original weight row width
#define NK 26             // K-steps of 32 (16 h + 10 e)
#define NKH 16
#define NKE 10

#define NRG 16            // row groups (batch split): 2 per XCD
#define ROWS 16           // batch rows per WG / group
#define NSPLIT 16         // n splits per row group
#define NW 32             // h columns per WG
#define WGS 256
#define THREADS 512

#define HROW_PAD 520      // padded LDS row in bf16 elems (1040 B)
#define HROW_B 1040
#define HBUF_HALF (B_SZ * H_SZ)   // bf16 elems per h buffer

typedef __bf16  bf16x8 __attribute__((ext_vector_type(8)));
typedef float   f32x4  __attribute__((ext_vector_type(4)));
typedef uint32_t u32x4 __attribute__((ext_vector_type(4)));

__device__ __forceinline__ float fsig(float x) { return 1.0f / (1.0f + __expf(-x)); }
__device__ __forceinline__ float ftanh_(float x) {
    float ax = fabsf(x);
    float e  = __expf(-2.0f * ax);
    float r  = (1.0f - e) / (1.0f + e);
    return x < 0.0f ? -r : r;
}

// ---------------- setup kernels ----------------

// Gate-interleaved pack: Wp row gn' = n*4 + g  (n = h col, g = gate i/f/g/o).
__global__ void k_pack(const float* __restrict__ Wi, const float* __restrict__ Wf,
                       const float* __restrict__ Wg, const float* __restrict__ Wo,
                       __hip_bfloat16* __restrict__ Wp) {
    int idx = blockIdx.x * blockDim.x + threadIdx.x;
    int total = 4 * H_SZ * KTOT;
    for (int i = idx; i < total; i += gridDim.x * blockDim.x) {
        int k   = i % KTOT;
        int gnp = i / KTOT;
        int n = gnp >> 2, g = gnp & 3;
        const float* W = (g == 0) ? Wi : (g == 1) ? Wf : (g == 2) ? Wg : Wo;
        float v = 0.0f;
        if (k < KH) v = W[n * XS_W + k];
        else { int e = k - KH; if (e < E_SZ) v = W[n * XS_W + KH + e]; }
        Wp[(size_t)gnp * KTOT + k] = __float2bfloat16(v);
    }
}

__global__ void k_gather(const int* __restrict__ x, const float* __restrict__ embed,
                         __hip_bfloat16* __restrict__ ebf) {
    int cid = blockIdx.x * blockDim.x + threadIdx.x;   // chunk of 8 elems
    const int nch = T_SZ * B_SZ * (KE / 8);
    if (cid >= nch) return;
    int ch = cid % (KE / 8);
    int tb = cid / (KE / 8);
    int b = tb % B_SZ;
    int t = tb / B_SZ;
    int row = x[b * T_SZ + t];
    const float* er = embed + (size_t)row * E_SZ;
    __hip_bfloat16 v[8];
    int e0 = ch * 8;
#pragma unroll
    for (int j = 0; j < 8; ++j) {
        int e = e0 + j;
        float f = (e < E_SZ) ? er[e] : 0.0f;
        v[j] = __float2bfloat16(f);
    }
    *reinterpret_cast<ulonglong2*>(ebf + ((size_t)t * B_SZ + b) * KE + e0) =
        *reinterpret_cast<const ulonglong2*>(v);
}

// zero final_h, flags, census; compute capture step per row
__global__ void k_misc(const int* __restrict__ x, float* __restrict__ final_h,
                       int* __restrict__ tcap, int* __restrict__ flags,
                       int* __restrict__ cns) {
    int tid = blockIdx.x * blockDim.x + threadIdx.x;
    int n = gridDim.x * blockDim.x;
    for (int i = tid; i < B_SZ * H_SZ; i += n) final_h[i] = 0.0f;
    if (tid < NRG * NSPLIT) flags[tid] = 0;
    if (tid < 16) cns[tid] = 0;
    if (tid < B_SZ) {
        int len = 0;
        for (int t = 0; t < T_SZ; ++t) len += (x[tid * T_SZ + t] != PAD_IDX);
        int tf = (len > 0) ? (len - 1) : 0;
        tcap[tid] = (x[tid * T_SZ + tf] == PAD_IDX) ? -1 : tf;
    }
}

// ---------------- recurrent cooperative kernel ----------------
// 256 WGs x 512 thr. 16 row groups x 16 WGs (2 groups/XCD on balanced
// placement). WG: rows b0..b0+15, h-cols n0..n0+31 (x4 gates, interleaved).
// Wave w: col quad w (cols n0+4w..+3), one 16x16 MFMA tile over gate-cols.
// After MFMA: in-wave 4x4 shuffle transpose puts all 4 gates of one
// (row,col) in one lane -> per-lane elementwise, c-state in VGPR.
// Sync: single-wave flag poll + barrier release; h via XCD-L2 (sc0) or
// agent-scope release/acquire fallback per placement census (G16-safe).
__global__ void __launch_bounds__(THREADS, 2)
k_lstm(const __hip_bfloat16* __restrict__ Wp, const __hip_bfloat16* __restrict__ ebf,
       const float* __restrict__ bi, const float* __restrict__ bfv,
       const float* __restrict__ bg, const float* __restrict__ bo,
       __hip_bfloat16* __restrict__ hbuf, float* __restrict__ final_h,
       const int* __restrict__ tcap, int* __restrict__ flags,
       int* __restrict__ cns) {
    __shared__ __align__(16) __hip_bfloat16 h_lds[ROWS * HROW_PAD];  // 16,640 B
    __shared__ int s_meta[3];

    const int tid  = threadIdx.x;
    const int w    = tid >> 6;
    const int lane = tid & 63;
    const int l15  = lane & 15;
    const int l4   = lane >> 4;
    const int cl   = l15 >> 2;      // col within quad
    const int p    = l15 & 3;       // (pre-transpose: gate; post: row sub-idx)

    // ---- placement census (once) ----
    if (tid == 0) {
        uint32_t xcc;
        asm volatile("s_getreg_b32 %0, hwreg(HW_REG_XCC_ID)" : "=s"(xcc));
        xcc &= 7;
        int ticket = __hip_atomic_fetch_add(&cns[xcc], 1, __ATOMIC_RELAXED,
                                            __HIP_MEMORY_SCOPE_AGENT);
        __hip_atomic_fetch_add(&cns[8], 1, __ATOMIC_RELEASE,
                               __HIP_MEMORY_SCOPE_AGENT);
        while (__hip_atomic_load(&cns[8], __ATOMIC_RELAXED,
                                 __HIP_MEMORY_SCOPE_AGENT) < WGS)
            __builtin_amdgcn_s_sleep(8);
        (void)__hip_atomic_load(&cns[8], __ATOMIC_ACQUIRE,
                                __HIP_MEMORY_SCOPE_AGENT);
        int bal = 1;
        for (int i = 0; i < 8; ++i)
            bal &= (__hip_atomic_load(&cns[i], __ATOMIC_RELAXED,
                                      __HIP_MEMORY_SCOPE_AGENT) == 32);
        s_meta[0] = bal ? (int)(xcc * 2 + (ticket >> 4)) : (int)(blockIdx.x >> 4);
        s_meta[1] = bal ? (ticket & 15) : (int)(blockIdx.x & 15);
        s_meta[2] = bal;
    }
    __syncthreads();
    const int rg   = s_meta[0];
    const int ns   = s_meta[1];
    const int fast = s_meta[2];
    const int b0   = rg * ROWS;
    const int n0   = ns * NW;

    // ---- weights (B-frag rows = n0*4 + w*16 + l15, gate-interleaved) ----
    bf16x8 wreg[NK];
    {
        const __hip_bfloat16* wB =
            Wp + ((size_t)(n0 * 4 + w * 16 + l15)) * KTOT + l4 * 8;
#pragma unroll
        for (int kk = 0; kk < NK; ++kk)
            wreg[kk] = *reinterpret_cast<const bf16x8*>(wB + kk * 32);
    }

    // per-lane output element: (row, col)
    const int col   = n0 + w * 4 + cl;
    const int row_l = l4 * 4 + p;
    const int row   = b0 + row_l;
    const float bib = bi[col], bfb = bfv[col], bgb = bg[col], bob = bo[col];
    const int   tcv = tcap[row];
    float creg = 0.0f;

    int* const fpoll = flags + rg * NSPLIT + (lane & 15);
    int* const fmine = flags + rg * NSPLIT + ns;
    char* const lw   = (char*)(&h_lds[0]) + (w * 2) * HROW_B + lane * 16;
    const char* hl_a = (const char*)(&h_lds[0]) + l15 * HROW_B + l4 * 16;
    uint16_t* const hst0 = (uint16_t*)hbuf + (size_t)row * H_SZ + col;

#pragma unroll 1
    for (int t = 0; t < T_SZ; ++t) {
        f32x4 acc0 = {0.f, 0.f, 0.f, 0.f};
        f32x4 acc1 = {0.f, 0.f, 0.f, 0.f};
        // e-part MFMAs (cached loads; A rows shared by all waves -> L1 hot)
        const __hip_bfloat16* ea =
            ebf + ((size_t)t * B_SZ + b0 + l15) * KE + l4 * 8;
#pragma unroll
        for (int kk = 0; kk < NKE; ++kk) {
            bf16x8 a = *reinterpret_cast<const bf16x8*>(ea + kk * 32);
            if (kk & 1) acc1 = __builtin_amdgcn_mfma_f32_16x16x32_bf16(a, wreg[NKH + kk], acc1, 0, 0, 0);
            else        acc0 = __builtin_amdgcn_mfma_f32_16x16x32_bf16(a, wreg[NKH + kk], acc0, 0, 0, 0);
        }
        if (t > 0) {
            // single-wave flag poll (flag >= t means h(t-1) data ready)
            if (w == 0) {
                const uint32_t want = (uint32_t)t;
                uint32_t fv;
                if (fast) {
                    for (;;) {
                        asm volatile("global_load_dword %0, %1, off sc0\n\t"
                                     "s_waitcnt vmcnt(0)"
                                     : "=&v"(fv)
                                     : "v"((uint64_t)(uintptr_t)fpoll) : "memory");
                        if (__all(fv >= want)) break;
                        __builtin_amdgcn_s_sleep(1);
                    }
                } else {
                    for (;;) {
                        fv = (uint32_t)__hip_atomic_load(fpoll, __ATOMIC_ACQUIRE,
                                                         __HIP_MEMORY_SCOPE_AGENT);
                        if (__all(fv >= want)) break;
                        __builtin_amdgcn_s_sleep(2);
                    }
                }
            }
            __syncthreads();   // release all waves once flags confirmed
            // bulk read 2 rows/wave (1 KB each) + stage to LDS
            const char* hb = (const char*)hbuf +
                             (size_t)((t - 1) & 1) * (HBUF_HALF * 2);
            if (fast) {
                u32x4 q0, q1;
                const char* dp = hb + (size_t)(b0 + w * 2) * 1024 + lane * 16;
                asm volatile(
                    "global_load_dwordx4 %0, %2, off sc0\n\t"
                    "global_load_dwordx4 %1, %2, off offset:1024 sc0\n\t"
                    "s_waitcnt vmcnt(0)"
                    : "=&v"(q0), "=&v"(q1)
                    : "v"((uint64_t)(uintptr_t)dp) : "memory");
                *reinterpret_cast<u32x4*>(lw)          = q0;
                *reinterpret_cast<u32x4*>(lw + HROW_B) = q1;
            } else {
                const uint64_t* qp =
                    (const uint64_t*)(hb + (size_t)(b0 + w * 2) * 1024) + lane;
                uint64_t a0 = *(const volatile uint64_t*)(qp);
                uint64_t a1 = *(const volatile uint64_t*)(qp + 64);
                uint64_t a2 = *(const volatile uint64_t*)(qp + 128);
                uint64_t a3 = *(const volatile uint64_t*)(qp + 192);
                *reinterpret_cast<uint64_t*>(lw + lane * 8 - lane * 16 + lane * 8)      = a0;  // lw+lane*8? keep explicit below
                // (rewritten explicitly for clarity)
                char* lwr = (char*)(&h_lds[0]) + (w * 2) * HROW_B;
                *reinterpret_cast<uint64_t*>(lwr + lane * 8)           = a0;
                *reinterpret_cast<uint64_t*>(lwr + 512 + lane * 8)     = a1;
                *reinterpret_cast<uint64_t*>(lwr + HROW_B + lane * 8)  = a2;
                *reinterpret_cast<uint64_t*>(lwr + HROW_B + 512 + lane * 8) = a3;
            }
            __syncthreads();   // h_lds ready
            // h-part MFMAs from LDS
#pragma unroll
            for (int kk = 0; kk < NKH; ++kk) {
                bf16x8 a = *reinterpret_cast<const bf16x8*>(hl_a + kk * 64);
                if (kk & 1) acc1 = __builtin_amdgcn_mfma_f32_16x16x32_bf16(a, wreg[kk], acc1, 0, 0, 0);
                else        acc0 = __builtin_amdgcn_mfma_f32_16x16x32_bf16(a, wreg[kk], acc0, 0, 0, 0);
            }
        }
        f32x4 acc = acc0 + acc1;
        // ---- in-wave 4x4 transpose: (gate g in lane, row j in reg) ->
        //      (row p in lane, gate j' in reg), among lanes differing in bits 0-1
        float v0 = acc[0], v1 = acc[1], v2 = acc[2], v3 = acc[3];
        const int gb = lane & 3;
        float t0 = __shfl_xor((gb & 1) ? v0 : v1, 1);
        float t1 = __shfl_xor((gb & 1) ? v2 : v3, 1);
        if (gb & 1) { v0 = t0; v2 = t1; } else { v1 = t0; v3 = t1; }
        t0 = __shfl_xor((gb & 2) ? v0 : v2, 2);
        t1 = __shfl_xor((gb & 2) ? v1 : v3, 2);
        if (gb & 2) { v0 = t0; v1 = t1; } else { v2 = t0; v3 = t1; }
        // v0..v3 = pre-acts of gates i,f,g,o for this lane's (row, col)
        float ig = fsig(v0 + bib);
        float fg = fsig(v1 + bfb);
        float gg = ftanh_(v2 + bgb);
        float og = fsig(v3 + bob);
        creg = fg * creg + ig * gg;
        float hv = ftanh_(creg) * og;
        uint16_t hu = __builtin_bit_cast(uint16_t, __float2bfloat16(hv));
        *(volatile uint16_t*)(hst0 + (size_t)(t & 1) * HBUF_HALF) = hu;
        if (t == tcv) final_h[(size_t)row * H_SZ + col] = hv;
        // drain stores, then publish flag t+1
        __syncthreads();
        if (tid == 0) {
            if (fast)
                *(volatile int*)fmine = t + 1;
            else
                __hip_atomic_store(fmine, t + 1, __ATOMIC_RELEASE,
                                   __HIP_MEMORY_SCOPE_AGENT);
        }
    }
}

// ---------------- output head ----------------
__global__ void k_out(const float* __restrict__ fin, const float* __restrict__ Wout,
                      const float* __restrict__ bout, float* __restrict__ out) {
    int b = blockIdx.x;
    int lane = threadIdx.x;  // 64
    float s0 = 0, s1 = 0, s2 = 0, s3 = 0, s4 = 0;
    const float* fr = fin + (size_t)b * H_SZ;
    for (int n = lane; n < H_SZ; n += 64) {
        float h = fr[n];
        s0 += h * Wout[0 * H_SZ + n];
        s1 += h * Wout[1 * H_SZ + n];
        s2 += h * Wout[2 * H_SZ + n];
        s3 += h * Wout[3 * H_SZ + n];
        s4 += h * Wout[4 * H_SZ + n];
    }
#pragma unroll
    for (int off = 32; off >= 1; off >>= 1) {
        s0 += __shfl_down(s0, off);
        s1 += __shfl_down(s1, off);
        s2 += __shfl_down(s2, off);
        s3 += __shfl_down(s3, off);
        s4 += __shfl_down(s4, off);
    }
    if (lane == 0) {
        out[b * O_SZ + 0] = s0 + bout[0];
        out[b * O_SZ + 1] = s1 + bout[1];
        out[b * O_SZ + 2] = s2 + bout[2];
        out[b * O_SZ + 3] = s3 + bout[3];
        out[b * O_SZ + 4] = s4 + bout[4];
    }
}

// ---------------- launch ----------------
extern "C" void kernel_launch(void* const* d_in, const int* in_sizes, int n_in,
                              void* d_out, int out_size, void* d_ws, size_t ws_size,
                              hipStream_t stream) {
    const int*   x     = (const int*)d_in[0];
    const float* embed = (const float*)d_in[1];
    const float* Wi    = (const float*)d_in[2];
    const float* bi    = (const float*)d_in[3];
    const float* Wf    = (const float*)d_in[4];
    const float* bfv   = (const float*)d_in[5];
    const float* Wg    = (const float*)d_in[6];
    const float* bg    = (const float*)d_in[7];
    const float* Wo    = (const float*)d_in[8];
    const float* bo    = (const float*)d_in[9];
    const float* Wout  = (const float*)d_in[10];
    const float* bout  = (const float*)d_in[11];
    float* out = (float*)d_out;

    char* ws = (char*)d_ws;
    size_t off = 0;
    auto alloc = [&](size_t bytes) {
        void* p = ws + off;
        off = (off + bytes + 255) & ~(size_t)255;
        return p;
    };
    __hip_bfloat16* Wp   = (__hip_bfloat16*)alloc((size_t)4 * H_SZ * KTOT * 2);
    __hip_bfloat16* ebf  = (__hip_bfloat16*)alloc((size_t)T_SZ * B_SZ * KE * 2);
    __hip_bfloat16* hbuf = (__hip_bfloat16*)alloc((size_t)2 * HBUF_HALF * 2);
    float* finh          = (float*)alloc((size_t)B_SZ * H_SZ * 4);
    int*   tcap          = (int*)alloc((size_t)B_SZ * 4);
    int*   flags         = (int*)alloc((size_t)NRG * NSPLIT * 4);
    int*   cns           = (int*)alloc((size_t)16 * 4);
    (void)ws_size; (void)in_sizes; (void)n_in; (void)out_size;

    k_pack<<<832, 256, 0, stream>>>(Wi, Wf, Wg, Wo, Wp);
    k_gather<<<(T_SZ * B_SZ * (KE / 8) + 255) / 256, 256, 0, stream>>>(x, embed, ebf);
    k_misc<<<128, 256, 0, stream>>>(x, finh, tcap, flags, cns);

    void* args[] = { &Wp, &ebf, &bi, &bfv, &bg, &bo, &hbuf, &finh, &tcap,
                     &flags, &cns };
    hipLaunchCooperativeKernel((void*)k_lstm, dim3(WGS), dim3(THREADS), args, 0, stream);

    k_out<<<B_SZ, 64, 0, stream>>>(finh, Wout, bout, out);
}

// Round 7
// 912.172 us; speedup vs baseline: 1.1007x; 1.1007x over previous
//
#include <hip/hip_runtime.h>
#include <hip/hip_bf16.h>
#include <stdint.h>

#define E_SZ 300
#define H_SZ 512
#define O_SZ 5
#define B_SZ 256
#define T_SZ 200
#define PAD_IDX 1

#define KH 512
#define KE 320            // padded e-width (300 -> 320)
#define KTOT 832          // 512 + 320
#define XS_W 812          // E + H, original weight row width
#define NK 26             // K-steps of 32 (16 h + 10 e)
#define NKH 16
#define NKE 10

#define NRG 16            // row groups (batch split): 2 per XCD
#define ROWS 16           // batch rows per WG / group
#define NSPLIT 16         // n splits per row group
#define NW 32             // h columns per WG
#define WGS 256
#define THREADS 512

#define HROW_PAD 520      // padded LDS row in bf16 elems (1040 B)
#define HROW_B 1040
#define HBUF_HALF (B_SZ * H_SZ)   // bf16 elems per h buffer

typedef __bf16  bf16x8 __attribute__((ext_vector_type(8)));
typedef float   f32x4  __attribute__((ext_vector_type(4)));
typedef uint32_t u32x4 __attribute__((ext_vector_type(4)));

__device__ __forceinline__ float fsig(float x) { return 1.0f / (1.0f + __expf(-x)); }
__device__ __forceinline__ float ftanh_(float x) {
    float ax = fabsf(x);
    float e  = __expf(-2.0f * ax);
    float r  = (1.0f - e) / (1.0f + e);
    return x < 0.0f ? -r : r;
}

// ---------------- setup kernels ----------------

// Gate-interleaved pack: Wp row gn' = n*4 + g  (n = h col, g = gate i/f/g/o).
__global__ void k_pack(const float* __restrict__ Wi, const float* __restrict__ Wf,
                       const float* __restrict__ Wg, const float* __restrict__ Wo,
                       __hip_bfloat16* __restrict__ Wp) {
    int idx = blockIdx.x * blockDim.x + threadIdx.x;
    int total = 4 * H_SZ * KTOT;
    for (int i = idx; i < total; i += gridDim.x * blockDim.x) {
        int k   = i % KTOT;
        int gnp = i / KTOT;
        int n = gnp >> 2, g = gnp & 3;
        const float* W = (g == 0) ? Wi : (g == 1) ? Wf : (g == 2) ? Wg : Wo;
        float v = 0.0f;
        if (k < KH) v = W[n * XS_W + k];
        else { int e = k - KH; if (e < E_SZ) v = W[n * XS_W + KH + e]; }
        Wp[(size_t)gnp * KTOT + k] = __float2bfloat16(v);
    }
}

__global__ void k_gather(const int* __restrict__ x, const float* __restrict__ embed,
                         __hip_bfloat16* __restrict__ ebf) {
    int cid = blockIdx.x * blockDim.x + threadIdx.x;   // chunk of 8 elems
    const int nch = T_SZ * B_SZ * (KE / 8);
    if (cid >= nch) return;
    int ch = cid % (KE / 8);
    int tb = cid / (KE / 8);
    int b = tb % B_SZ;
    int t = tb / B_SZ;
    int row = x[b * T_SZ + t];
    const float* er = embed + (size_t)row * E_SZ;
    __hip_bfloat16 v[8];
    int e0 = ch * 8;
#pragma unroll
    for (int j = 0; j < 8; ++j) {
        int e = e0 + j;
        float f = (e < E_SZ) ? er[e] : 0.0f;
        v[j] = __float2bfloat16(f);
    }
    *reinterpret_cast<ulonglong2*>(ebf + ((size_t)t * B_SZ + b) * KE + e0) =
        *reinterpret_cast<const ulonglong2*>(v);
}

// zero final_h, flags, census; compute capture step per row
__global__ void k_misc(const int* __restrict__ x, float* __restrict__ final_h,
                       int* __restrict__ tcap, int* __restrict__ flags,
                       int* __restrict__ cns) {
    int tid = blockIdx.x * blockDim.x + threadIdx.x;
    int n = gridDim.x * blockDim.x;
    for (int i = tid; i < B_SZ * H_SZ; i += n) final_h[i] = 0.0f;
    if (tid < NRG * NSPLIT) flags[tid] = 0;
    if (tid < 16) cns[tid] = 0;
    if (tid < B_SZ) {
        int len = 0;
        for (int t = 0; t < T_SZ; ++t) len += (x[tid * T_SZ + t] != PAD_IDX);
        int tf = (len > 0) ? (len - 1) : 0;
        tcap[tid] = (x[tid * T_SZ + tf] == PAD_IDX) ? -1 : tf;
    }
}

// ---------------- recurrent cooperative kernel ----------------
// 256 WGs x 512 thr. 16 row groups x 16 WGs (2 groups/XCD on balanced
// placement). WG: rows b0..b0+15, h-cols n0..n0+31 (x4 gates, interleaved).
// Wave w: col quad w, one 16x16 MFMA tile; in-wave 4x4 shuffle transpose
// puts all 4 gates of one (row,col) in one lane -> per-lane elementwise,
// c-state in VGPR. h exchange: PLAIN dword stores (stay in XCD L2, R5-proven)
// + volatile flag publish; consumers sc0-poll flags then sc0 bulk-read.
// Agent-scope atomics fallback if placement census is unbalanced (G16-safe).
__global__ void __launch_bounds__(THREADS, 2)
k_lstm(const __hip_bfloat16* __restrict__ Wp, const __hip_bfloat16* __restrict__ ebf,
       const float* __restrict__ bi, const float* __restrict__ bfv,
       const float* __restrict__ bg, const float* __restrict__ bo,
       __hip_bfloat16* __restrict__ hbuf, float* __restrict__ final_h,
       const int* __restrict__ tcap, int* __restrict__ flags,
       int* __restrict__ cns) {
    __shared__ __align__(16) __hip_bfloat16 h_lds[ROWS * HROW_PAD];  // 16,640 B
    __shared__ int s_meta[3];

    const int tid  = threadIdx.x;
    const int w    = tid >> 6;
    const int lane = tid & 63;
    const int l15  = lane & 15;
    const int l4   = lane >> 4;
    const int cl   = l15 >> 2;      // col within quad
    const int p    = l15 & 3;       // (pre-transpose: gate; post: row sub-idx)

    // ---- placement census (once) ----
    if (tid == 0) {
        uint32_t xcc;
        asm volatile("s_getreg_b32 %0, hwreg(HW_REG_XCC_ID)" : "=s"(xcc));
        xcc &= 7;
        int ticket = __hip_atomic_fetch_add(&cns[xcc], 1, __ATOMIC_RELAXED,
                                            __HIP_MEMORY_SCOPE_AGENT);
        __hip_atomic_fetch_add(&cns[8], 1, __ATOMIC_RELEASE,
                               __HIP_MEMORY_SCOPE_AGENT);
        while (__hip_atomic_load(&cns[8], __ATOMIC_RELAXED,
                                 __HIP_MEMORY_SCOPE_AGENT) < WGS)
            __builtin_amdgcn_s_sleep(8);
        (void)__hip_atomic_load(&cns[8], __ATOMIC_ACQUIRE,
                                __HIP_MEMORY_SCOPE_AGENT);
        int bal = 1;
        for (int i = 0; i < 8; ++i)
            bal &= (__hip_atomic_load(&cns[i], __ATOMIC_RELAXED,
                                      __HIP_MEMORY_SCOPE_AGENT) == 32);
        s_meta[0] = bal ? (int)(xcc * 2 + (ticket >> 4)) : (int)(blockIdx.x >> 4);
        s_meta[1] = bal ? (ticket & 15) : (int)(blockIdx.x & 15);
        s_meta[2] = bal;
    }
    __syncthreads();
    const int rg   = s_meta[0];
    const int ns   = s_meta[1];
    const int fast = s_meta[2];
    const int b0   = rg * ROWS;
    const int n0   = ns * NW;

    // ---- weights (B-frag rows = n0*4 + w*16 + l15, gate-interleaved) ----
    bf16x8 wreg[NK];
    {
        const __hip_bfloat16* wB =
            Wp + ((size_t)(n0 * 4 + w * 16 + l15)) * KTOT + l4 * 8;
#pragma unroll
        for (int kk = 0; kk < NK; ++kk)
            wreg[kk] = *reinterpret_cast<const bf16x8*>(wB + kk * 32);
    }

    // per-lane output element: (row, col)
    const int col   = n0 + w * 4 + cl;
    const int row_l = l4 * 4 + p;
    const int row   = b0 + row_l;
    const float bib = bi[col], bfb = bfv[col], bgb = bg[col], bob = bo[col];
    const int   tcv = tcap[row];
    float creg = 0.0f;

    int* const fpoll = flags + rg * NSPLIT + (lane & 15);
    int* const fmine = flags + rg * NSPLIT + ns;
    const char* hl_a = (const char*)(&h_lds[0]) + l15 * HROW_B + l4 * 16;
    // packed-dword store index (lanes with cl even store cols col, col+1)
    uint32_t* const hst_dw =
        (uint32_t*)hbuf + ((size_t)row * H_SZ + n0) / 2 + 2 * w + (cl >> 1);

#pragma unroll 1
    for (int t = 0; t < T_SZ; ++t) {
        f32x4 acc0 = {0.f, 0.f, 0.f, 0.f};
        f32x4 acc1 = {0.f, 0.f, 0.f, 0.f};
        // e-part MFMAs (cached loads; A rows shared by all waves -> L1 hot)
        const __hip_bfloat16* ea =
            ebf + ((size_t)t * B_SZ + b0 + l15) * KE + l4 * 8;
#pragma unroll
        for (int kk = 0; kk < NKE; ++kk) {
            bf16x8 a = *reinterpret_cast<const bf16x8*>(ea + kk * 32);
            if (kk & 1) acc1 = __builtin_amdgcn_mfma_f32_16x16x32_bf16(a, wreg[NKH + kk], acc1, 0, 0, 0);
            else        acc0 = __builtin_amdgcn_mfma_f32_16x16x32_bf16(a, wreg[NKH + kk], acc0, 0, 0, 0);
        }
        if (t > 0) {
            // single-wave flag poll (flag >= t means h(t-1) data ready)
            if (w == 0) {
                const uint32_t want = (uint32_t)t;
                uint32_t fv;
                if (fast) {
                    for (;;) {
                        asm volatile("global_load_dword %0, %1, off sc0\n\t"
                                     "s_waitcnt vmcnt(0)"
                                     : "=&v"(fv)
                                     : "v"((uint64_t)(uintptr_t)fpoll) : "memory");
                        if (__all(fv >= want)) break;
                        __builtin_amdgcn_s_sleep(1);
                    }
                } else {
                    for (;;) {
                        fv = (uint32_t)__hip_atomic_load(fpoll, __ATOMIC_ACQUIRE,
                                                         __HIP_MEMORY_SCOPE_AGENT);
                        if (__all(fv >= want)) break;
                        __builtin_amdgcn_s_sleep(2);
                    }
                }
            }
            __syncthreads();   // release all waves once flags confirmed
            // bulk read 2 rows/wave (1 KB each) + stage to LDS
            const char* hb = (const char*)hbuf +
                             (size_t)((t - 1) & 1) * (HBUF_HALF * 2);
            char* const lwr = (char*)(&h_lds[0]) + (w * 2) * HROW_B;
            if (fast) {
                u32x4 q0, q1;
                const char* dp = hb + (size_t)(b0 + w * 2) * 1024 + lane * 16;
                asm volatile(
                    "global_load_dwordx4 %0, %2, off sc0\n\t"
                    "global_load_dwordx4 %1, %2, off offset:1024 sc0\n\t"
                    "s_waitcnt vmcnt(0)"
                    : "=&v"(q0), "=&v"(q1)
                    : "v"((uint64_t)(uintptr_t)dp) : "memory");
                *reinterpret_cast<u32x4*>(lwr + lane * 16)          = q0;
                *reinterpret_cast<u32x4*>(lwr + HROW_B + lane * 16) = q1;
            } else {
                const uint64_t* qp =
                    (const uint64_t*)(hb + (size_t)(b0 + w * 2) * 1024) + lane;
                uint64_t a0 = __hip_atomic_load(qp,       __ATOMIC_RELAXED, __HIP_MEMORY_SCOPE_AGENT);
                uint64_t a1 = __hip_atomic_load(qp + 64,  __ATOMIC_RELAXED, __HIP_MEMORY_SCOPE_AGENT);
                uint64_t a2 = __hip_atomic_load(qp + 128, __ATOMIC_RELAXED, __HIP_MEMORY_SCOPE_AGENT);
                uint64_t a3 = __hip_atomic_load(qp + 192, __ATOMIC_RELAXED, __HIP_MEMORY_SCOPE_AGENT);
                *reinterpret_cast<uint64_t*>(lwr + lane * 8)                = a0;
                *reinterpret_cast<uint64_t*>(lwr + 512 + lane * 8)          = a1;
                *reinterpret_cast<uint64_t*>(lwr + HROW_B + lane * 8)       = a2;
                *reinterpret_cast<uint64_t*>(lwr + HROW_B + 512 + lane * 8) = a3;
            }
            __syncthreads();   // h_lds ready
            // h-part MFMAs from LDS
#pragma unroll
            for (int kk = 0; kk < NKH; ++kk) {
                bf16x8 a = *reinterpret_cast<const bf16x8*>(hl_a + kk * 64);
                if (kk & 1) acc1 = __builtin_amdgcn_mfma_f32_16x16x32_bf16(a, wreg[kk], acc1, 0, 0, 0);
                else        acc0 = __builtin_amdgcn_mfma_f32_16x16x32_bf16(a, wreg[kk], acc0, 0, 0, 0);
            }
        }
        f32x4 acc = acc0 + acc1;
        // ---- in-wave 4x4 transpose: (gate in lane bits0-1, row in reg) ->
        //      (row in lane bits0-1, gate in reg)
        float v0 = acc[0], v1 = acc[1], v2 = acc[2], v3 = acc[3];
        const int gb = lane & 3;
        float t0 = __shfl_xor((gb & 1) ? v0 : v1, 1);
        float t1 = __shfl_xor((gb & 1) ? v2 : v3, 1);
        if (gb & 1) { v0 = t0; v2 = t1; } else { v1 = t0; v3 = t1; }
        t0 = __shfl_xor((gb & 2) ? v0 : v2, 2);
        t1 = __shfl_xor((gb & 2) ? v1 : v3, 2);
        if (gb & 2) { v0 = t0; v1 = t1; } else { v2 = t0; v3 = t1; }
        // v0..v3 = pre-acts of gates i,f,g,o for this lane's (row, col)
        float ig = fsig(v0 + bib);
        float fg = fsig(v1 + bfb);
        float gg = ftanh_(v2 + bgb);
        float og = fsig(v3 + bob);
        creg = fg * creg + ig * gg;
        float hv = ftanh_(creg) * og;
        // pack even/odd col pair into one dword via partner lane (lane^4)
        uint32_t hu = (uint32_t)__builtin_bit_cast(uint16_t, __float2bfloat16(hv));
        uint32_t hup = __shfl_xor((int)hu, 4);
        if ((lane & 4) == 0) {
            uint32_t pk = hu | (hup << 16);
            uint32_t* dst = hst_dw + (size_t)(t & 1) * (HBUF_HALF / 2);
            if (fast)
                __hip_atomic_store(dst, pk, __ATOMIC_RELAXED,
                                   __HIP_MEMORY_SCOPE_WORKGROUP);   // plain, L2
            else
                __hip_atomic_store(dst, pk, __ATOMIC_RELAXED,
                                   __HIP_MEMORY_SCOPE_AGENT);
        }
        if (t == tcv) final_h[(size_t)row * H_SZ + col] = hv;
        // drain stores (syncthreads waits vmcnt), then publish flag t+1
        __syncthreads();
        if (tid == 0) {
            if (fast)
                *(volatile int*)fmine = t + 1;   // sc0 sc1: cross-CU visible
            else
                __hip_atomic_store(fmine, t + 1, __ATOMIC_RELEASE,
                                   __HIP_MEMORY_SCOPE_AGENT);
        }
    }
}

// ---------------- output head ----------------
__global__ void k_out(const float* __restrict__ fin, const float* __restrict__ Wout,
                      const float* __restrict__ bout, float* __restrict__ out) {
    int b = blockIdx.x;
    int lane = threadIdx.x;  // 64
    float s0 = 0, s1 = 0, s2 = 0, s3 = 0, s4 = 0;
    const float* fr = fin + (size_t)b * H_SZ;
    for (int n = lane; n < H_SZ; n += 64) {
        float h = fr[n];
        s0 += h * Wout[0 * H_SZ + n];
        s1 += h * Wout[1 * H_SZ + n];
        s2 += h * Wout[2 * H_SZ + n];
        s3 += h * Wout[3 * H_SZ + n];
        s4 += h * Wout[4 * H_SZ + n];
    }
#pragma unroll
    for (int off = 32; off >= 1; off >>= 1) {
        s0 += __shfl_down(s0, off);
        s1 += __shfl_down(s1, off);
        s2 += __shfl_down(s2, off);
        s3 += __shfl_down(s3, off);
        s4 += __shfl_down(s4, off);
    }
    if (lane == 0) {
        out[b * O_SZ + 0] = s0 + bout[0];
        out[b * O_SZ + 1] = s1 + bout[1];
        out[b * O_SZ + 2] = s2 + bout[2];
        out[b * O_SZ + 3] = s3 + bout[3];
        out[b * O_SZ + 4] = s4 + bout[4];
    }
}

// ---------------- launch ----------------
extern "C" void kernel_launch(void* const* d_in, const int* in_sizes, int n_in,
                              void* d_out, int out_size, void* d_ws, size_t ws_size,
                              hipStream_t stream) {
    const int*   x     = (const int*)d_in[0];
    const float* embed = (const float*)d_in[1];
    const float* Wi    = (const float*)d_in[2];
    const float* bi    = (const float*)d_in[3];
    const float* Wf    = (const float*)d_in[4];
    const float* bfv   = (const float*)d_in[5];
    const float* Wg    = (const float*)d_in[6];
    const float* bg    = (const float*)d_in[7];
    const float* Wo    = (const float*)d_in[8];
    const float* bo    = (const float*)d_in[9];
    const float* Wout  = (const float*)d_in[10];
    const float* bout  = (const float*)d_in[11];
    float* out = (float*)d_out;

    char* ws = (char*)d_ws;
    size_t off = 0;
    auto alloc = [&](size_t bytes) {
        void* p = ws + off;
        off = (off + bytes + 255) & ~(size_t)255;
        return p;
    };
    __hip_bfloat16* Wp   = (__hip_bfloat16*)alloc((size_t)4 * H_SZ * KTOT * 2);
    __hip_bfloat16* ebf  = (__hip_bfloat16*)alloc((size_t)T_SZ * B_SZ * KE * 2);
    __hip_bfloat16* hbuf = (__hip_bfloat16*)alloc((size_t)2 * HBUF_HALF * 2);
    float* finh          = (float*)alloc((size_t)B_SZ * H_SZ * 4);
    int*   tcap          = (int*)alloc((size_t)B_SZ * 4);
    int*   flags         = (int*)alloc((size_t)NRG * NSPLIT * 4);
    int*   cns           = (int*)alloc((size_t)16 * 4);
    (void)ws_size; (void)in_sizes; (void)n_in; (void)out_size;

    k_pack<<<832, 256, 0, stream>>>(Wi, Wf, Wg, Wo, Wp);
    k_gather<<<(T_SZ * B_SZ * (KE / 8) + 255) / 256, 256, 0, stream>>>(x, embed, ebf);
    k_misc<<<128, 256, 0, stream>>>(x, finh, tcap, flags, cns);

    void* args[] = { &Wp, &ebf, &bi, &bfv, &bg, &bo, &hbuf, &finh, &tcap,
                     &flags, &cns };
    hipLaunchCooperativeKernel((void*)k_lstm, dim3(WGS), dim3(THREADS), args, 0, stream);

    k_out<<<B_SZ, 64, 0, stream>>>(finh, Wout, bout, out);
}

// Round 10
// 842.685 us; speedup vs baseline: 1.1914x; 1.0825x over previous
//
#include <hip/hip_runtime.h>
#include <hip/hip_bf16.h>
#include <stdint.h>

#define E_SZ 300
#define H_SZ 512
#define O_SZ 5
#define B_SZ 256
#define T_SZ 200
#define PAD_IDX 1

#define KH 512
#define KE 320            // padded e-width (300 -> 320)
#define KTOT 832          // 512 + 320
#define XS_W 812          // E + H, original weight row width
#define NK 26             // K-steps of 32 (16 h + 10 e)
#define NKH 16
#define NKE 10

#define NRG 16            // row groups (batch split): 2 per XCD
#define ROWS 16           // batch rows per WG / group
#define NSPLIT 16         // n splits per row group
#define NW 32             // h columns per WG
#define WGS 256
#define THREADS 512

#define HROW_PAD 520      // padded LDS row in bf16 elems (1040 B)
#define HROW_B 1040
#define HBUF_HALF (B_SZ * H_SZ)   // bf16 elems per h buffer

typedef __bf16  bf16x8 __attribute__((ext_vector_type(8)));
typedef float   f32x4  __attribute__((ext_vector_type(4)));
typedef uint32_t u32x4 __attribute__((ext_vector_type(4)));

__device__ __forceinline__ float fsig(float x) { return 1.0f / (1.0f + __expf(-x)); }
__device__ __forceinline__ float ftanh_(float x) {
    float ax = fabsf(x);
    float e  = __expf(-2.0f * ax);
    float r  = (1.0f - e) / (1.0f + e);
    return x < 0.0f ? -r : r;
}

// ---------------- setup kernels ----------------

// Gate-interleaved pack: Wp row gn' = n*4 + g  (n = h col, g = gate i/f/g/o).
__global__ void k_pack(const float* __restrict__ Wi, const float* __restrict__ Wf,
                       const float* __restrict__ Wg, const float* __restrict__ Wo,
                       __hip_bfloat16* __restrict__ Wp) {
    int idx = blockIdx.x * blockDim.x + threadIdx.x;
    int total = 4 * H_SZ * KTOT;
    for (int i = idx; i < total; i += gridDim.x * blockDim.x) {
        int k   = i % KTOT;
        int gnp = i / KTOT;
        int n = gnp >> 2, g = gnp & 3;
        const float* W = (g == 0) ? Wi : (g == 1) ? Wf : (g == 2) ? Wg : Wo;
        float v = 0.0f;
        if (k < KH) v = W[n * XS_W + k];
        else { int e = k - KH; if (e < E_SZ) v = W[n * XS_W + KH + e]; }
        Wp[(size_t)gnp * KTOT + k] = __float2bfloat16(v);
    }
}

__global__ void k_gather(const int* __restrict__ x, const float* __restrict__ embed,
                         __hip_bfloat16* __restrict__ ebf) {
    int cid = blockIdx.x * blockDim.x + threadIdx.x;   // chunk of 8 elems
    const int nch = T_SZ * B_SZ * (KE / 8);
    if (cid >= nch) return;
    int ch = cid % (KE / 8);
    int tb = cid / (KE / 8);
    int b = tb % B_SZ;
    int t = tb / B_SZ;
    int row = x[b * T_SZ + t];
    const float* er = embed + (size_t)row * E_SZ;
    __hip_bfloat16 v[8];
    int e0 = ch * 8;
#pragma unroll
    for (int j = 0; j < 8; ++j) {
        int e = e0 + j;
        float f = (e < E_SZ) ? er[e] : 0.0f;
        v[j] = __float2bfloat16(f);
    }
    *reinterpret_cast<ulonglong2*>(ebf + ((size_t)t * B_SZ + b) * KE + e0) =
        *reinterpret_cast<const ulonglong2*>(v);
}

// zero final_h, flags, census; compute capture step per row
__global__ void k_misc(const int* __restrict__ x, float* __restrict__ final_h,
                       int* __restrict__ tcap, int* __restrict__ flags,
                       int* __restrict__ cns) {
    int tid = blockIdx.x * blockDim.x + threadIdx.x;
    int n = gridDim.x * blockDim.x;
    for (int i = tid; i < B_SZ * H_SZ; i += n) final_h[i] = 0.0f;
    if (tid < NRG * NSPLIT) flags[tid] = 0;
    if (tid < 16) cns[tid] = 0;
    if (tid < B_SZ) {
        int len = 0;
        for (int t = 0; t < T_SZ; ++t) len += (x[tid * T_SZ + t] != PAD_IDX);
        int tf = (len > 0) ? (len - 1) : 0;
        tcap[tid] = (x[tid * T_SZ + tf] == PAD_IDX) ? -1 : tf;
    }
}

// ---------------- recurrent cooperative kernel ----------------
// Structure identical to the proven 865us kernel (R7). Changes:
// (1) waves_per_eu(2,2): VGPR cap 256 guaranteed (schedulable: 8-wave WG needs
//     2 waves/SIMD), and no allocator incentive to shrink below it;
// (2) weight fragments laundered through opaque asm -> non-rematerializable ->
//     register-resident (R5-R7 ran at VGPR=80 < 104 needed: weights were
//     re-streamed from L2 every step, ~1.4us/step — the dominant floor);
// (3) fast-path flag publish via plain workgroup-scope store (stays in XCD L2,
//     visible to same-XCD sc0 polls; removes the MALL round-trip).
__global__ void
__attribute__((amdgpu_flat_work_group_size(THREADS, THREADS),
               amdgpu_waves_per_eu(2, 2)))
k_lstm(const __hip_bfloat16* __restrict__ Wp, const __hip_bfloat16* __restrict__ ebf,
       const float* __restrict__ bi, const float* __restrict__ bfv,
       const float* __restrict__ bg, const float* __restrict__ bo,
       __hip_bfloat16* __restrict__ hbuf, float* __restrict__ final_h,
       const int* __restrict__ tcap, int* __restrict__ flags,
       int* __restrict__ cns) {
    __shared__ __align__(16) __hip_bfloat16 h_lds[ROWS * HROW_PAD];  // 16,640 B
    __shared__ int s_meta[3];

    const int tid  = threadIdx.x;
    const int w    = tid >> 6;
    const int lane = tid & 63;
    const int l15  = lane & 15;
    const int l4   = lane >> 4;
    const int cl   = l15 >> 2;

    // ---- placement census (once) ----
    if (tid == 0) {
        uint32_t xcc;
        asm volatile("s_getreg_b32 %0, hwreg(HW_REG_XCC_ID)" : "=s"(xcc));
        xcc &= 7;
        int ticket = __hip_atomic_fetch_add(&cns[xcc], 1, __ATOMIC_RELAXED,
                                            __HIP_MEMORY_SCOPE_AGENT);
        __hip_atomic_fetch_add(&cns[8], 1, __ATOMIC_RELEASE,
                               __HIP_MEMORY_SCOPE_AGENT);
        while (__hip_atomic_load(&cns[8], __ATOMIC_RELAXED,
                                 __HIP_MEMORY_SCOPE_AGENT) < WGS)
            __builtin_amdgcn_s_sleep(8);
        (void)__hip_atomic_load(&cns[8], __ATOMIC_ACQUIRE,
                                __HIP_MEMORY_SCOPE_AGENT);
        int bal = 1;
        for (int i = 0; i < 8; ++i)
            bal &= (__hip_atomic_load(&cns[i], __ATOMIC_RELAXED,
                                      __HIP_MEMORY_SCOPE_AGENT) == 32);
        s_meta[0] = bal ? (int)(xcc * 2 + (ticket >> 4)) : (int)(blockIdx.x >> 4);
        s_meta[1] = bal ? (ticket & 15) : (int)(blockIdx.x & 15);
        s_meta[2] = bal;
    }
    __syncthreads();
    const int rg   = s_meta[0];
    const int ns   = s_meta[1];
    const int fast = s_meta[2];
    const int b0   = rg * ROWS;
    const int n0   = ns * NW;

    // ---- weights (B-frag rows = n0*4 + w*16 + l15, gate-interleaved) ----
    // Laundered through opaque asm: non-rematerializable -> stays in VGPRs.
    bf16x8 wreg[NK];
    {
        const __hip_bfloat16* wB =
            Wp + ((size_t)(n0 * 4 + w * 16 + l15)) * KTOT + l4 * 8;
#pragma unroll
        for (int kk = 0; kk < NK; ++kk) {
            u32x4 v = *reinterpret_cast<const u32x4*>(wB + kk * 32);
            asm volatile("" : "+v"(v));
            wreg[kk] = __builtin_bit_cast(bf16x8, v);
        }
    }

    // per-lane output element: (row, col)
    const int col   = n0 + w * 4 + cl;
    const int row   = b0 + l4 * 4 + (l15 & 3);
    const float bib = bi[col], bfb = bfv[col], bgb = bg[col], bob = bo[col];
    const int   tcv = tcap[row];
    float creg = 0.0f;

    int* const fq    = flags + rg * NSPLIT;
    int* const fmine = fq + ns;
    const uint64_t fp = (uint64_t)(uintptr_t)(fq + (lane & 15));
    char* const lwr  = (char*)(&h_lds[0]) + (w * 2) * HROW_B;
    const char* hl_a = (const char*)(&h_lds[0]) + l15 * HROW_B + l4 * 16;
    uint32_t* const hst_dw =
        (uint32_t*)hbuf + ((size_t)row * H_SZ + n0) / 2 + 2 * w + (cl >> 1);

#pragma unroll 1
    for (int t = 0; t < T_SZ; ++t) {
        f32x4 acc0 = {0.f, 0.f, 0.f, 0.f};
        f32x4 acc1 = {0.f, 0.f, 0.f, 0.f};
        // e-part MFMAs (cached loads; A rows shared by all waves -> L1 hot)
        const __hip_bfloat16* ea =
            ebf + ((size_t)t * B_SZ + b0 + l15) * KE + l4 * 8;
#pragma unroll
        for (int kk = 0; kk < NKE; ++kk) {
            bf16x8 a = *reinterpret_cast<const bf16x8*>(ea + kk * 32);
            if (kk & 1) acc1 = __builtin_amdgcn_mfma_f32_16x16x32_bf16(a, wreg[NKH + kk], acc1, 0, 0, 0);
            else        acc0 = __builtin_amdgcn_mfma_f32_16x16x32_bf16(a, wreg[NKH + kk], acc0, 0, 0, 0);
        }
        if (t > 0) {
            // single-wave flag poll (flag >= t means h(t-1) data ready)
            if (w == 0) {
                const uint32_t want = (uint32_t)t;
                uint32_t fv;
                if (fast) {
                    for (;;) {
                        asm volatile("global_load_dword %0, %1, off sc0\n\t"
                                     "s_waitcnt vmcnt(0)"
                                     : "=&v"(fv) : "v"(fp) : "memory");
                        if (__all(fv >= want)) break;
                        __builtin_amdgcn_s_sleep(1);
                    }
                } else {
                    const int* fpl = fq + (lane & 15);
                    for (;;) {
                        fv = (uint32_t)__hip_atomic_load(fpl, __ATOMIC_ACQUIRE,
                                                         __HIP_MEMORY_SCOPE_AGENT);
                        if (__all(fv >= want)) break;
                        __builtin_amdgcn_s_sleep(2);
                    }
                }
            }
            __syncthreads();   // B1: flags confirmed for whole WG
            // bulk read 2 rows/wave (1 KB each) + stage to LDS
            const char* hb = (const char*)hbuf +
                             (size_t)((t - 1) & 1) * (HBUF_HALF * 2);
            if (fast) {
                u32x4 q0, q1;
                const char* dp = hb + (size_t)(b0 + w * 2) * 1024 + lane * 16;
                asm volatile(
                    "global_load_dwordx4 %0, %2, off sc0\n\t"
                    "global_load_dwordx4 %1, %2, off offset:1024 sc0\n\t"
                    "s_waitcnt vmcnt(0)"
                    : "=&v"(q0), "=&v"(q1)
                    : "v"((uint64_t)(uintptr_t)dp) : "memory");
                *reinterpret_cast<u32x4*>(lwr + lane * 16)          = q0;
                *reinterpret_cast<u32x4*>(lwr + HROW_B + lane * 16) = q1;
            } else {
                const uint64_t* qp =
                    (const uint64_t*)(hb + (size_t)(b0 + w * 2) * 1024) + lane;
                uint64_t a0 = __hip_atomic_load(qp,       __ATOMIC_RELAXED, __HIP_MEMORY_SCOPE_AGENT);
                uint64_t a1 = __hip_atomic_load(qp + 64,  __ATOMIC_RELAXED, __HIP_MEMORY_SCOPE_AGENT);
                uint64_t a2 = __hip_atomic_load(qp + 128, __ATOMIC_RELAXED, __HIP_MEMORY_SCOPE_AGENT);
                uint64_t a3 = __hip_atomic_load(qp + 192, __ATOMIC_RELAXED, __HIP_MEMORY_SCOPE_AGENT);
                *reinterpret_cast<uint64_t*>(lwr + lane * 8)                = a0;
                *reinterpret_cast<uint64_t*>(lwr + 512 + lane * 8)          = a1;
                *reinterpret_cast<uint64_t*>(lwr + HROW_B + lane * 8)       = a2;
                *reinterpret_cast<uint64_t*>(lwr + HROW_B + 512 + lane * 8) = a3;
            }
            __syncthreads();   // B2: h_lds ready
            // h-part MFMAs from LDS
#pragma unroll
            for (int kk = 0; kk < NKH; ++kk) {
                bf16x8 a = *reinterpret_cast<const bf16x8*>(hl_a + kk * 64);
                if (kk & 1) acc1 = __builtin_amdgcn_mfma_f32_16x16x32_bf16(a, wreg[kk], acc1, 0, 0, 0);
                else        acc0 = __builtin_amdgcn_mfma_f32_16x16x32_bf16(a, wreg[kk], acc0, 0, 0, 0);
            }
        }
        f32x4 acc = acc0 + acc1;
        // ---- in-wave 4x4 transpose: (gate in lane bits0-1, row in reg) ->
        //      (row in lane bits0-1, gate in reg)
        float v0 = acc[0], v1 = acc[1], v2 = acc[2], v3 = acc[3];
        const int gb = lane & 3;
        float t0 = __shfl_xor((gb & 1) ? v0 : v1, 1);
        float t1 = __shfl_xor((gb & 1) ? v2 : v3, 1);
        if (gb & 1) { v0 = t0; v2 = t1; } else { v1 = t0; v3 = t1; }
        t0 = __shfl_xor((gb & 2) ? v0 : v2, 2);
        t1 = __shfl_xor((gb & 2) ? v1 : v3, 2);
        if (gb & 2) { v0 = t0; v1 = t1; } else { v2 = t0; v3 = t1; }
        // v0..v3 = pre-acts of gates i,f,g,o for this lane's (row, col)
        float ig = fsig(v0 + bib);
        float fg = fsig(v1 + bfb);
        float gg = ftanh_(v2 + bgb);
        float og = fsig(v3 + bob);
        creg = fg * creg + ig * gg;
        float hv = ftanh_(creg) * og;
        // pack even/odd col pair into one dword via partner lane (lane^4)
        uint32_t hu = (uint32_t)__builtin_bit_cast(uint16_t, __float2bfloat16(hv));
        uint32_t hup = __shfl_xor((int)hu, 4);
        if ((lane & 4) == 0) {
            uint32_t pk = hu | (hup << 16);
            uint32_t* dst = hst_dw + (size_t)(t & 1) * (HBUF_HALF / 2);
            if (fast)
                __hip_atomic_store(dst, pk, __ATOMIC_RELAXED,
                                   __HIP_MEMORY_SCOPE_WORKGROUP);   // plain, L2
            else
                __hip_atomic_store(dst, pk, __ATOMIC_RELAXED,
                                   __HIP_MEMORY_SCOPE_AGENT);
        }
        if (t == tcv) final_h[(size_t)row * H_SZ + col] = hv;
        // B3: drains all stores, then publish flag t+1
        __syncthreads();
        if (tid == 0) {
            if (fast)
                __hip_atomic_store(fmine, t + 1, __ATOMIC_RELAXED,
                                   __HIP_MEMORY_SCOPE_WORKGROUP);   // plain, L2
            else
                __hip_atomic_store(fmine, t + 1, __ATOMIC_RELEASE,
                                   __HIP_MEMORY_SCOPE_AGENT);
        }
    }
}

// ---------------- output head ----------------
__global__ void k_out(const float* __restrict__ fin, const float* __restrict__ Wout,
                      const float* __restrict__ bout, float* __restrict__ out) {
    int b = blockIdx.x;
    int lane = threadIdx.x;  // 64
    float s0 = 0, s1 = 0, s2 = 0, s3 = 0, s4 = 0;
    const float* fr = fin + (size_t)b * H_SZ;
    for (int n = lane; n < H_SZ; n += 64) {
        float h = fr[n];
        s0 += h * Wout[0 * H_SZ + n];
        s1 += h * Wout[1 * H_SZ + n];
        s2 += h * Wout[2 * H_SZ + n];
        s3 += h * Wout[3 * H_SZ + n];
        s4 += h * Wout[4 * H_SZ + n];
    }
#pragma unroll
    for (int off = 32; off >= 1; off >>= 1) {
        s0 += __shfl_down(s0, off);
        s1 += __shfl_down(s1, off);
        s2 += __shfl_down(s2, off);
        s3 += __shfl_down(s3, off);
        s4 += __shfl_down(s4, off);
    }
    if (lane == 0) {
        out[b * O_SZ + 0] = s0 + bout[0];
        out[b * O_SZ + 1] = s1 + bout[1];
        out[b * O_SZ + 2] = s2 + bout[2];
        out[b * O_SZ + 3] = s3 + bout[3];
        out[b * O_SZ + 4] = s4 + bout[4];
    }
}

// ---------------- launch ----------------
extern "C" void kernel_launch(void* const* d_in, const int* in_sizes, int n_in,
                              void* d_out, int out_size, void* d_ws, size_t ws_size,
                              hipStream_t stream) {
    const int*   x     = (const int*)d_in[0];
    const float* embed = (const float*)d_in[1];
    const float* Wi    = (const float*)d_in[2];
    const float* bi    = (const float*)d_in[3];
    const float* Wf    = (const float*)d_in[4];
    const float* bfv   = (const float*)d_in[5];
    const float* Wg    = (const float*)d_in[6];
    const float* bg    = (const float*)d_in[7];
    const float* Wo    = (const float*)d_in[8];
    const float* bo    = (const float*)d_in[9];
    const float* Wout  = (const float*)d_in[10];
    const float* bout  = (const float*)d_in[11];
    float* out = (float*)d_out;

    char* ws = (char*)d_ws;
    size_t off = 0;
    auto alloc = [&](size_t bytes) {
        void* p = ws + off;
        off = (off + bytes + 255) & ~(size_t)255;
        return p;
    };
    __hip_bfloat16* Wp   = (__hip_bfloat16*)alloc((size_t)4 * H_SZ * KTOT * 2);
    __hip_bfloat16* ebf  = (__hip_bfloat16*)alloc((size_t)T_SZ * B_SZ * KE * 2);
    __hip_bfloat16* hbuf = (__hip_bfloat16*)alloc((size_t)2 * HBUF_HALF * 2);
    float* finh          = (float*)alloc((size_t)B_SZ * H_SZ * 4);
    int*   tcap          = (int*)alloc((size_t)B_SZ * 4);
    int*   flags         = (int*)alloc((size_t)NRG * NSPLIT * 4);
    int*   cns           = (int*)alloc((size_t)16 * 4);
    (void)ws_size; (void)in_sizes; (void)n_in; (void)out_size;

    k_pack<<<832, 256, 0, stream>>>(Wi, Wf, Wg, Wo, Wp);
    k_gather<<<(T_SZ * B_SZ * (KE / 8) + 255) / 256, 256, 0, stream>>>(x, embed, ebf);
    k_misc<<<128, 256, 0, stream>>>(x, finh, tcap, flags, cns);

    void* args[] = { &Wp, &ebf, &bi, &bfv, &bg, &bo, &hbuf, &finh, &tcap,
                     &flags, &cns };
    hipLaunchCooperativeKernel((void*)k_lstm, dim3(WGS), dim3(THREADS), args, 0, stream);

    k_out<<<B_SZ, 64, 0, stream>>>(finh, Wout, bout, out);
}

// Round 11
// 839.503 us; speedup vs baseline: 1.1960x; 1.0038x over previous
//
#include <hip/hip_runtime.h>
#include <hip/hip_bf16.h>
#include <stdint.h>

#define E_SZ 300
#define H_SZ 512
#define O_SZ 5
#define B_SZ 256
#define T_SZ 200
#define PAD_IDX 1

#define KH 512
#define KE 320            // padded e-width (300 -> 320)
#define KTOT 832          // 512 + 320
#define XS_W 812          // E + H, original weight row width
#define NK 26             // K-steps of 32 (16 h + 10 e)
#define NKH 16
#define NKE 10

#define NRG 16            // row groups (batch split): 2 per XCD
#define ROWS 16           // batch rows per WG / group
#define NSPLIT 16         // n splits per row group
#define NW 32             // h columns per WG
#define WGS 256
#define THREADS 512

#define HROW_PAD 520      // padded LDS row in bf16 elems (1040 B)
#define HROW_B 1040
#define HBUF_HALF (B_SZ * H_SZ)   // bf16 elems per h buffer

// LDS bloat: 84 KB > 160/2 KB forces the compiler's occupancy model to
// 1 WG/CU = 2 waves/EU -> VGPR pressure target 256 (the knob launch_bounds/
// waves_per_eu failed to turn in R7/R10; resource math is what it respects).
// Runtime cost: none (grid is 1 WG/CU anyway).
#define SMEM_BYTES (84 * 1024)

typedef __bf16  bf16x8 __attribute__((ext_vector_type(8)));
typedef float   f32x4  __attribute__((ext_vector_type(4)));
typedef uint32_t u32x4 __attribute__((ext_vector_type(4)));

__device__ __forceinline__ float fsig(float x) { return 1.0f / (1.0f + __expf(-x)); }
__device__ __forceinline__ float ftanh_(float x) {
    float ax = fabsf(x);
    float e  = __expf(-2.0f * ax);
    float r  = (1.0f - e) / (1.0f + e);
    return x < 0.0f ? -r : r;
}

// ---------------- setup kernels ----------------

// Gate-interleaved pack: Wp row gn' = n*4 + g  (n = h col, g = gate i/f/g/o).
__global__ void k_pack(const float* __restrict__ Wi, const float* __restrict__ Wf,
                       const float* __restrict__ Wg, const float* __restrict__ Wo,
                       __hip_bfloat16* __restrict__ Wp) {
    int idx = blockIdx.x * blockDim.x + threadIdx.x;
    int total = 4 * H_SZ * KTOT;
    for (int i = idx; i < total; i += gridDim.x * blockDim.x) {
        int k   = i % KTOT;
        int gnp = i / KTOT;
        int n = gnp >> 2, g = gnp & 3;
        const float* W = (g == 0) ? Wi : (g == 1) ? Wf : (g == 2) ? Wg : Wo;
        float v = 0.0f;
        if (k < KH) v = W[n * XS_W + k];
        else { int e = k - KH; if (e < E_SZ) v = W[n * XS_W + KH + e]; }
        Wp[(size_t)gnp * KTOT + k] = __float2bfloat16(v);
    }
}

__global__ void k_gather(const int* __restrict__ x, const float* __restrict__ embed,
                         __hip_bfloat16* __restrict__ ebf) {
    int cid = blockIdx.x * blockDim.x + threadIdx.x;   // chunk of 8 elems
    const int nch = T_SZ * B_SZ * (KE / 8);
    if (cid >= nch) return;
    int ch = cid % (KE / 8);
    int tb = cid / (KE / 8);
    int b = tb % B_SZ;
    int t = tb / B_SZ;
    int row = x[b * T_SZ + t];
    const float* er = embed + (size_t)row * E_SZ;
    __hip_bfloat16 v[8];
    int e0 = ch * 8;
#pragma unroll
    for (int j = 0; j < 8; ++j) {
        int e = e0 + j;
        float f = (e < E_SZ) ? er[e] : 0.0f;
        v[j] = __float2bfloat16(f);
    }
    *reinterpret_cast<ulonglong2*>(ebf + ((size_t)t * B_SZ + b) * KE + e0) =
        *reinterpret_cast<const ulonglong2*>(v);
}

// zero final_h, flags, census; compute capture step per row
__global__ void k_misc(const int* __restrict__ x, float* __restrict__ final_h,
                       int* __restrict__ tcap, int* __restrict__ flags,
                       int* __restrict__ cns) {
    int tid = blockIdx.x * blockDim.x + threadIdx.x;
    int n = gridDim.x * blockDim.x;
    for (int i = tid; i < B_SZ * H_SZ; i += n) final_h[i] = 0.0f;
    if (tid < NRG * NSPLIT) flags[tid] = 0;
    if (tid < 16) cns[tid] = 0;
    if (tid < B_SZ) {
        int len = 0;
        for (int t = 0; t < T_SZ; ++t) len += (x[tid * T_SZ + t] != PAD_IDX);
        int tf = (len > 0) ? (len - 1) : 0;
        tcap[tid] = (x[tid * T_SZ + tf] == PAD_IDX) ? -1 : tf;
    }
}

// ---------------- recurrent cooperative kernel ----------------
// Byte-identical logic to the passing R10 kernel. Changes:
// (1) static LDS bloated to 84 KB (occupancy model -> 1 WG/CU -> VGPR budget
//     256) so the laundered 104-VGPR weight set finally stays resident;
// (2) __launch_bounds__(512, 2) (schedulable: 8-wave WG at <=256 VGPR).
__global__ void __launch_bounds__(THREADS, 2)
k_lstm(const __hip_bfloat16* __restrict__ Wp, const __hip_bfloat16* __restrict__ ebf,
       const float* __restrict__ bi, const float* __restrict__ bfv,
       const float* __restrict__ bg, const float* __restrict__ bo,
       __hip_bfloat16* __restrict__ hbuf, float* __restrict__ final_h,
       const int* __restrict__ tcap, int* __restrict__ flags,
       int* __restrict__ cns) {
    __shared__ __align__(16) char smem[SMEM_BYTES];
    __hip_bfloat16* const h_lds = (__hip_bfloat16*)smem;      // 16,640 B used
    int* const s_meta = (int*)(smem + ROWS * HROW_B);         // +12 B

    const int tid  = threadIdx.x;
    const int w    = tid >> 6;
    const int lane = tid & 63;
    const int l15  = lane & 15;
    const int l4   = lane >> 4;
    const int cl   = l15 >> 2;

    // ---- placement census (once) ----
    if (tid == 0) {
        uint32_t xcc;
        asm volatile("s_getreg_b32 %0, hwreg(HW_REG_XCC_ID)" : "=s"(xcc));
        xcc &= 7;
        int ticket = __hip_atomic_fetch_add(&cns[xcc], 1, __ATOMIC_RELAXED,
                                            __HIP_MEMORY_SCOPE_AGENT);
        __hip_atomic_fetch_add(&cns[8], 1, __ATOMIC_RELEASE,
                               __HIP_MEMORY_SCOPE_AGENT);
        while (__hip_atomic_load(&cns[8], __ATOMIC_RELAXED,
                                 __HIP_MEMORY_SCOPE_AGENT) < WGS)
            __builtin_amdgcn_s_sleep(8);
        (void)__hip_atomic_load(&cns[8], __ATOMIC_ACQUIRE,
                                __HIP_MEMORY_SCOPE_AGENT);
        int bal = 1;
        for (int i = 0; i < 8; ++i)
            bal &= (__hip_atomic_load(&cns[i], __ATOMIC_RELAXED,
                                      __HIP_MEMORY_SCOPE_AGENT) == 32);
        s_meta[0] = bal ? (int)(xcc * 2 + (ticket >> 4)) : (int)(blockIdx.x >> 4);
        s_meta[1] = bal ? (ticket & 15) : (int)(blockIdx.x & 15);
        s_meta[2] = bal;
    }
    __syncthreads();
    const int rg   = s_meta[0];
    const int ns   = s_meta[1];
    const int fast = s_meta[2];
    const int b0   = rg * ROWS;
    const int n0   = ns * NW;

    // ---- weights (B-frag rows = n0*4 + w*16 + l15, gate-interleaved) ----
    // Laundered through opaque asm: non-rematerializable -> stays in VGPRs
    // now that the budget allows it.
    bf16x8 wreg[NK];
    {
        const __hip_bfloat16* wB =
            Wp + ((size_t)(n0 * 4 + w * 16 + l15)) * KTOT + l4 * 8;
#pragma unroll
        for (int kk = 0; kk < NK; ++kk) {
            u32x4 v = *reinterpret_cast<const u32x4*>(wB + kk * 32);
            asm volatile("" : "+v"(v));
            wreg[kk] = __builtin_bit_cast(bf16x8, v);
        }
    }

    // per-lane output element: (row, col)
    const int col   = n0 + w * 4 + cl;
    const int row   = b0 + l4 * 4 + (l15 & 3);
    const float bib = bi[col], bfb = bfv[col], bgb = bg[col], bob = bo[col];
    const int   tcv = tcap[row];
    float creg = 0.0f;

    int* const fq    = flags + rg * NSPLIT;
    int* const fmine = fq + ns;
    const uint64_t fp = (uint64_t)(uintptr_t)(fq + (lane & 15));
    char* const lwr  = (char*)(&h_lds[0]) + (w * 2) * HROW_B;
    const char* hl_a = (const char*)(&h_lds[0]) + l15 * HROW_B + l4 * 16;
    uint32_t* const hst_dw =
        (uint32_t*)hbuf + ((size_t)row * H_SZ + n0) / 2 + 2 * w + (cl >> 1);

#pragma unroll 1
    for (int t = 0; t < T_SZ; ++t) {
        f32x4 acc0 = {0.f, 0.f, 0.f, 0.f};
        f32x4 acc1 = {0.f, 0.f, 0.f, 0.f};
        // e-part MFMAs (cached loads; A rows shared by all waves -> L1 hot)
        const __hip_bfloat16* ea =
            ebf + ((size_t)t * B_SZ + b0 + l15) * KE + l4 * 8;
#pragma unroll
        for (int kk = 0; kk < NKE; ++kk) {
            bf16x8 a = *reinterpret_cast<const bf16x8*>(ea + kk * 32);
            if (kk & 1) acc1 = __builtin_amdgcn_mfma_f32_16x16x32_bf16(a, wreg[NKH + kk], acc1, 0, 0, 0);
            else        acc0 = __builtin_amdgcn_mfma_f32_16x16x32_bf16(a, wreg[NKH + kk], acc0, 0, 0, 0);
        }
        if (t > 0) {
            // single-wave flag poll (flag >= t means h(t-1) data ready)
            if (w == 0) {
                const uint32_t want = (uint32_t)t;
                uint32_t fv;
                if (fast) {
                    for (;;) {
                        asm volatile("global_load_dword %0, %1, off sc0\n\t"
                                     "s_waitcnt vmcnt(0)"
                                     : "=&v"(fv) : "v"(fp) : "memory");
                        if (__all(fv >= want)) break;
                        __builtin_amdgcn_s_sleep(1);
                    }
                } else {
                    const int* fpl = fq + (lane & 15);
                    for (;;) {
                        fv = (uint32_t)__hip_atomic_load(fpl, __ATOMIC_ACQUIRE,
                                                         __HIP_MEMORY_SCOPE_AGENT);
                        if (__all(fv >= want)) break;
                        __builtin_amdgcn_s_sleep(2);
                    }
                }
            }
            __syncthreads();   // B1: flags confirmed for whole WG
            // bulk read 2 rows/wave (1 KB each) + stage to LDS
            const char* hb = (const char*)hbuf +
                             (size_t)((t - 1) & 1) * (HBUF_HALF * 2);
            if (fast) {
                u32x4 q0, q1;
                const char* dp = hb + (size_t)(b0 + w * 2) * 1024 + lane * 16;
                asm volatile(
                    "global_load_dwordx4 %0, %2, off sc0\n\t"
                    "global_load_dwordx4 %1, %2, off offset:1024 sc0\n\t"
                    "s_waitcnt vmcnt(0)"
                    : "=&v"(q0), "=&v"(q1)
                    : "v"((uint64_t)(uintptr_t)dp) : "memory");
                *reinterpret_cast<u32x4*>(lwr + lane * 16)          = q0;
                *reinterpret_cast<u32x4*>(lwr + HROW_B + lane * 16) = q1;
            } else {
                const uint64_t* qp =
                    (const uint64_t*)(hb + (size_t)(b0 + w * 2) * 1024) + lane;
                uint64_t a0 = __hip_atomic_load(qp,       __ATOMIC_RELAXED, __HIP_MEMORY_SCOPE_AGENT);
                uint64_t a1 = __hip_atomic_load(qp + 64,  __ATOMIC_RELAXED, __HIP_MEMORY_SCOPE_AGENT);
                uint64_t a2 = __hip_atomic_load(qp + 128, __ATOMIC_RELAXED, __HIP_MEMORY_SCOPE_AGENT);
                uint64_t a3 = __hip_atomic_load(qp + 192, __ATOMIC_RELAXED, __HIP_MEMORY_SCOPE_AGENT);
                *reinterpret_cast<uint64_t*>(lwr + lane * 8)                = a0;
                *reinterpret_cast<uint64_t*>(lwr + 512 + lane * 8)          = a1;
                *reinterpret_cast<uint64_t*>(lwr + HROW_B + lane * 8)       = a2;
                *reinterpret_cast<uint64_t*>(lwr + HROW_B + 512 + lane * 8) = a3;
            }
            __syncthreads();   // B2: h_lds ready
            // h-part MFMAs from LDS
#pragma unroll
            for (int kk = 0; kk < NKH; ++kk) {
                bf16x8 a = *reinterpret_cast<const bf16x8*>(hl_a + kk * 64);
                if (kk & 1) acc1 = __builtin_amdgcn_mfma_f32_16x16x32_bf16(a, wreg[kk], acc1, 0, 0, 0);
                else        acc0 = __builtin_amdgcn_mfma_f32_16x16x32_bf16(a, wreg[kk], acc0, 0, 0, 0);
            }
        }
        f32x4 acc = acc0 + acc1;
        // ---- in-wave 4x4 transpose: (gate in lane bits0-1, row in reg) ->
        //      (row in lane bits0-1, gate in reg)
        float v0 = acc[0], v1 = acc[1], v2 = acc[2], v3 = acc[3];
        const int gb = lane & 3;
        float t0 = __shfl_xor((gb & 1) ? v0 : v1, 1);
        float t1 = __shfl_xor((gb & 1) ? v2 : v3, 1);
        if (gb & 1) { v0 = t0; v2 = t1; } else { v1 = t0; v3 = t1; }
        t0 = __shfl_xor((gb & 2) ? v0 : v2, 2);
        t1 = __shfl_xor((gb & 2) ? v1 : v3, 2);
        if (gb & 2) { v0 = t0; v1 = t1; } else { v2 = t0; v3 = t1; }
        // v0..v3 = pre-acts of gates i,f,g,o for this lane's (row, col)
        float ig = fsig(v0 + bib);
        float fg = fsig(v1 + bfb);
        float gg = ftanh_(v2 + bgb);
        float og = fsig(v3 + bob);
        creg = fg * creg + ig * gg;
        float hv = ftanh_(creg) * og;
        // pack even/odd col pair into one dword via partner lane (lane^4)
        uint32_t hu = (uint32_t)__builtin_bit_cast(uint16_t, __float2bfloat16(hv));
        uint32_t hup = __shfl_xor((int)hu, 4);
        if ((lane & 4) == 0) {
            uint32_t pk = hu | (hup << 16);
            uint32_t* dst = hst_dw + (size_t)(t & 1) * (HBUF_HALF / 2);
            if (fast)
                __hip_atomic_store(dst, pk, __ATOMIC_RELAXED,
                                   __HIP_MEMORY_SCOPE_WORKGROUP);   // plain, L2
            else
                __hip_atomic_store(dst, pk, __ATOMIC_RELAXED,
                                   __HIP_MEMORY_SCOPE_AGENT);
        }
        if (t == tcv) final_h[(size_t)row * H_SZ + col] = hv;
        // B3: drains all stores, then publish flag t+1
        __syncthreads();
        if (tid == 0) {
            if (fast)
                __hip_atomic_store(fmine, t + 1, __ATOMIC_RELAXED,
                                   __HIP_MEMORY_SCOPE_WORKGROUP);   // plain, L2
            else
                __hip_atomic_store(fmine, t + 1, __ATOMIC_RELEASE,
                                   __HIP_MEMORY_SCOPE_AGENT);
        }
    }
}

// ---------------- output head ----------------
__global__ void k_out(const float* __restrict__ fin, const float* __restrict__ Wout,
                      const float* __restrict__ bout, float* __restrict__ out) {
    int b = blockIdx.x;
    int lane = threadIdx.x;  // 64
    float s0 = 0, s1 = 0, s2 = 0, s3 = 0, s4 = 0;
    const float* fr = fin + (size_t)b * H_SZ;
    for (int n = lane; n < H_SZ; n += 64) {
        float h = fr[n];
        s0 += h * Wout[0 * H_SZ + n];
        s1 += h * Wout[1 * H_SZ + n];
        s2 += h * Wout[2 * H_SZ + n];
        s3 += h * Wout[3 * H_SZ + n];
        s4 += h * Wout[4 * H_SZ + n];
    }
#pragma unroll
    for (int off = 32; off >= 1; off >>= 1) {
        s0 += __shfl_down(s0, off);
        s1 += __shfl_down(s1, off);
        s2 += __shfl_down(s2, off);
        s3 += __shfl_down(s3, off);
        s4 += __shfl_down(s4, off);
    }
    if (lane == 0) {
        out[b * O_SZ + 0] = s0 + bout[0];
        out[b * O_SZ + 1] = s1 + bout[1];
        out[b * O_SZ + 2] = s2 + bout[2];
        out[b * O_SZ + 3] = s3 + bout[3];
        out[b * O_SZ + 4] = s4 + bout[4];
    }
}

// ---------------- launch ----------------
extern "C" void kernel_launch(void* const* d_in, const int* in_sizes, int n_in,
                              void* d_out, int out_size, void* d_ws, size_t ws_size,
                              hipStream_t stream) {
    const int*   x     = (const int*)d_in[0];
    const float* embed = (const float*)d_in[1];
    const float* Wi    = (const float*)d_in[2];
    const float* bi    = (const float*)d_in[3];
    const float* Wf    = (const float*)d_in[4];
    const float* bfv   = (const float*)d_in[5];
    const float* Wg    = (const float*)d_in[6];
    const float* bg    = (const float*)d_in[7];
    const float* Wo    = (const float*)d_in[8];
    const float* bo    = (const float*)d_in[9];
    const float* Wout  = (const float*)d_in[10];
    const float* bout  = (const float*)d_in[11];
    float* out = (float*)d_out;

    char* ws = (char*)d_ws;
    size_t off = 0;
    auto alloc = [&](size_t bytes) {
        void* p = ws + off;
        off = (off + bytes + 255) & ~(size_t)255;
        return p;
    };
    __hip_bfloat16* Wp   = (__hip_bfloat16*)alloc((size_t)4 * H_SZ * KTOT * 2);
    __hip_bfloat16* ebf  = (__hip_bfloat16*)alloc((size_t)T_SZ * B_SZ * KE * 2);
    __hip_bfloat16* hbuf = (__hip_bfloat16*)alloc((size_t)2 * HBUF_HALF * 2);
    float* finh          = (float*)alloc((size_t)B_SZ * H_SZ * 4);
    int*   tcap          = (int*)alloc((size_t)B_SZ * 4);
    int*   flags         = (int*)alloc((size_t)NRG * NSPLIT * 4);
    int*   cns           = (int*)alloc((size_t)16 * 4);
    (void)ws_size; (void)in_sizes; (void)n_in; (void)out_size;

    k_pack<<<832, 256, 0, stream>>>(Wi, Wf, Wg, Wo, Wp);
    k_gather<<<(T_SZ * B_SZ * (KE / 8) + 255) / 256, 256, 0, stream>>>(x, embed, ebf);
    k_misc<<<128, 256, 0, stream>>>(x, finh, tcap, flags, cns);

    void* args[] = { &Wp, &ebf, &bi, &bfv, &bg, &bo, &hbuf, &finh, &tcap,
                     &flags, &cns };
    hipLaunchCooperativeKernel((void*)k_lstm, dim3(WGS), dim3(THREADS), args, 0, stream);

    k_out<<<B_SZ, 64, 0, stream>>>(finh, Wout, bout, out);
}